// Round 2
// baseline (6851.961 us; speedup 1.0000x reference)
//
#include <hip/hip_runtime.h>
#include <hip/hip_bf16.h>

// Problem constants
#define B_   64
#define T_   512
#define I_   512
#define H_   512
#define G_   5
#define NROW 2560   // G*H gate rows per direction
#define KD   512    // K depth (I or H)
#define NBLK_REC 128

typedef __attribute__((ext_vector_type(8))) __bf16 bf16x8;
typedef __attribute__((ext_vector_type(4))) float  f32x4;

#define MFMA16(A, Bf, C) __builtin_amdgcn_mfma_f32_16x16x32_bf16(A, Bf, C, 0, 0, 0)

__device__ __forceinline__ unsigned short f2bf(float f) {
  unsigned u = __builtin_bit_cast(unsigned, f);
  u = (u + 0x7fffu + ((u >> 16) & 1u)) >> 16;   // RNE
  return (unsigned short)u;
}
__device__ __forceinline__ float bf2f(unsigned short s) {
  unsigned u = ((unsigned)s) << 16;
  return __builtin_bit_cast(float, u);
}
__device__ __forceinline__ float sigm(float x) { return 1.f / (1.f + __expf(-x)); }

// ---------------- ws layout (bytes) ----------------
// xp     : [2][T][NROW][B] bf16   = 335,544,320
// x_bf16 : [B][T][I]      bf16   =  33,554,432
// W2x    : [2][NROW][KD]  bf16   =   5,242,880
// W2h    : [2][NROW][KD]  bf16   =   5,242,880
// bias2  : [2][NROW]      f32    =      20,480
// hbuf   : [2][2][B][H]   bf16   =     262,144
// barrier: 4096 B
#define OFF_XP   ((size_t)0)
#define OFF_XB   ((size_t)335544320)
#define OFF_W2X  ((size_t)369098752)
#define OFF_W2H  ((size_t)374341632)
#define OFF_BIAS ((size_t)379584512)
#define OFF_HB   ((size_t)379604992)
#define OFF_BAR  ((size_t)379867136)
#define WS_NEED  ((size_t)379871232)

// ---------------- sentinel (ws too small) ----------------
__global__ void k_sentinel(float* out, int n) {
  int i = blockIdx.x * 256 + threadIdx.x;
  if (i < n) out[i] = 10000.0f;
}

// ---------------- converts ----------------
__global__ void k_cvt_weights(const float* __restrict__ Wx_f, const float* __restrict__ Wh_f,
                              const float* __restrict__ Wx_b, const float* __restrict__ Wh_b,
                              const float* __restrict__ bx_f, const float* __restrict__ bh_f,
                              const float* __restrict__ bx_b, const float* __restrict__ bh_b,
                              unsigned short* __restrict__ W2x, unsigned short* __restrict__ W2h,
                              float* __restrict__ bias2) {
  int idx = blockIdx.x * 256 + threadIdx.x;       // exactly 2*NROW*KD threads
  int dir = idx / (NROW * KD);
  int r   = idx % (NROW * KD);
  W2x[idx] = f2bf(dir ? Wx_b[r] : Wx_f[r]);
  W2h[idx] = f2bf(dir ? Wh_b[r] : Wh_f[r]);
  if (idx < 2 * NROW) {
    int d2 = idx / NROW, n = idx % NROW;
    bias2[idx] = d2 ? (bx_b[n] + bh_b[n]) : (bx_f[n] + bh_f[n]);
  }
}

__global__ void k_cvt_x(const float* __restrict__ x, unsigned short* __restrict__ xb) {
  int idx = blockIdx.x * 256 + threadIdx.x;       // exactly B*T*I threads
  xb[idx] = f2bf(x[idx]);
}

__global__ void k_zero_h(unsigned short* __restrict__ hb, unsigned* __restrict__ bar) {
  int idx = blockIdx.x * 256 + threadIdx.x;       // exactly 2*2*B*H threads
  hb[idx] = 0;
  if (idx < 1024) bar[idx] = 0;
}

// ---------------- phase 1: xp = Wx · x^T (+bias), both dirs ----------------
// GEMM: M-dim = n (2560 rows of W), N-dim = m = s*64+b (32768), K = 512.
// 128x128 tile, BK=64, 4 waves, each wave a 64x64 quadrant of 4x4 16x16 frags.
__global__ __launch_bounds__(256) void k_gemm_xp(
    const unsigned short* __restrict__ W2x,   // [2][NROW][KD]
    const unsigned short* __restrict__ xb,    // [B][T][I]
    const float* __restrict__ bias2,          // [2][NROW]
    unsigned short* __restrict__ xp)          // [2][T][NROW][B]
{
  const int tid = threadIdx.x;
  const int lane = tid & 63, wv = tid >> 6;
  int bz = blockIdx.x;
  const int dir = bz / (20 * 256); bz %= (20 * 256);
  const int nblk = bz / 256, mblk = bz % 256;
  const int n0 = nblk * 128, m0 = mblk * 128;
  const int l15 = lane & 15, l4 = lane >> 4;
  const int nh = wv >> 1, mh = wv & 1;

  __shared__ unsigned short Al[128 * 72];
  __shared__ unsigned short Bl[128 * 72];

  const unsigned short* Wd = W2x + (size_t)dir * NROW * KD;

  f32x4 acc[4][4];
  f32x4 zz = {0.f, 0.f, 0.f, 0.f};
#pragma unroll
  for (int i = 0; i < 4; ++i)
#pragma unroll
    for (int j = 0; j < 4; ++j) acc[i][j] = zz;

  for (int k0 = 0; k0 < KD; k0 += 64) {
    // stage A (W rows) and B (x rows): 1024 16B segments each, lane-consecutive
#pragma unroll
    for (int j = 0; j < 4; ++j) {
      int sg = j * 256 + tid;
      int row = sg >> 3, ko = (sg & 7) * 8;
      bf16x8 va = *(const bf16x8*)(Wd + (size_t)(n0 + row) * KD + k0 + ko);
      *(bf16x8*)(Al + row * 72 + ko) = va;
      int m = m0 + row;
      int ss = m >> 6, b = m & 63;
      int trow = dir ? (T_ - 1 - ss) : ss;
      bf16x8 vb = *(const bf16x8*)(xb + ((size_t)b * T_ + trow) * I_ + k0 + ko);
      *(bf16x8*)(Bl + row * 72 + ko) = vb;
    }
    __syncthreads();
#pragma unroll
    for (int kk = 0; kk < 2; ++kk) {
      bf16x8 af[4], bfr[4];
#pragma unroll
      for (int f = 0; f < 4; ++f) {
        af[f]  = *(const bf16x8*)(Al + (nh * 64 + f * 16 + l15) * 72 + kk * 32 + l4 * 8);
        bfr[f] = *(const bf16x8*)(Bl + (mh * 64 + f * 16 + l15) * 72 + kk * 32 + l4 * 8);
      }
#pragma unroll
      for (int fi = 0; fi < 4; ++fi)
#pragma unroll
        for (int fj = 0; fj < 4; ++fj)
          acc[fi][fj] = MFMA16(af[fi], bfr[fj], acc[fi][fj]);
    }
    __syncthreads();
  }

  // epilogue: D row = n (M), col = m (N); add bias, store bf16 to xp[dir][s][n][b]
#pragma unroll
  for (int fi = 0; fi < 4; ++fi) {
#pragma unroll
    for (int fj = 0; fj < 4; ++fj) {
#pragma unroll
      for (int r = 0; r < 4; ++r) {
        int n = n0 + nh * 64 + fi * 16 + l4 * 4 + r;
        int m = m0 + mh * 64 + fj * 16 + l15;
        int ss = m >> 6, b = m & 63;
        float v = acc[fi][fj][r] + bias2[dir * NROW + n];
        xp[(((size_t)dir * T_ + ss) * NROW + n) * 64 + b] = f2bf(v);
      }
    }
  }
}

// ---------------- device-scope grid barrier (no cooperative launch) ----------------
// Monotonic counter: block arrives (release fence + relaxed add), spins until
// cnt >= NBLK_REC*(step+1), then acquire fence. Counter zeroed per launch.
__device__ __forceinline__ void grid_barrier(unsigned* cnt, int step) {
  __syncthreads();
  if (threadIdx.x == 0) {
    __builtin_amdgcn_fence(__ATOMIC_RELEASE, "agent");
    __hip_atomic_fetch_add(cnt, 1u, __ATOMIC_RELAXED, __HIP_MEMORY_SCOPE_AGENT);
    unsigned target = (unsigned)(NBLK_REC * (step + 1));
    while (__hip_atomic_load(cnt, __ATOMIC_RELAXED, __HIP_MEMORY_SCOPE_AGENT) < target) {
      __builtin_amdgcn_s_sleep(2);
    }
    __builtin_amdgcn_fence(__ATOMIC_ACQUIRE, "agent");
  }
  __syncthreads();
}

// ---------------- phase 2: persistent recurrent kernel ----------------
// 128 blocks (dir = bid&1, ublk = bid>>1 owns 8 units), 256 threads = 4 waves.
// Wave wv = batch tile (16 rows). Wh frags live in registers for all 512 steps.
// Gate rows local r in [0,40): g = r>>3, unit = ublk*8 + (r&7); 3 N-tiles (pad to 48).
__global__ __launch_bounds__(256, 1) void k_recurrent(
    const unsigned short* __restrict__ W2h,  // [2][NROW][KD]
    const unsigned short* __restrict__ xp,   // [2][T][NROW][B]
    unsigned short* __restrict__ hbuf,       // [2][2][B][H]
    float* __restrict__ out,                 // [B][T][2H]
    unsigned* __restrict__ bar)
{
  const int tid = threadIdx.x;
  const int lane = tid & 63, wv = tid >> 6;
  const int bid = blockIdx.x;
  const int dir = bid & 1;
  const int ublk = bid >> 1;
  const int l15 = lane & 15, l4 = lane >> 4;

  __shared__ float gate_lds[64][52];

  f32x4 zz = {0.f, 0.f, 0.f, 0.f};
  const bf16x8 zfrag = __builtin_bit_cast(bf16x8, zz);

  // preload recurrent-weight fragments into registers: wfrag[nt][ks]
  bf16x8 wfrag[3][16];
#pragma unroll
  for (int nt = 0; nt < 3; ++nt) {
    int r = nt * 16 + l15;
#pragma unroll
    for (int ks = 0; ks < 16; ++ks) {
      if (r < 40) {
        int g = r >> 3, ul = r & 7;
        const unsigned short* wrow =
            W2h + ((size_t)dir * NROW + g * H_ + ublk * 8 + ul) * KD;
        wfrag[nt][ks] = *(const bf16x8*)(wrow + ks * 32 + l4 * 8);
      } else {
        wfrag[nt][ks] = zfrag;
      }
    }
  }

  // persistent cell state: thread owns cells c0=tid, c1=tid+256 (c = b*8 + ul)
  float kst0 = 0.f, kpst0 = 0.f, kst1 = 0.f, kpst1 = 0.f;
  const int b0 = tid >> 3, ul0 = tid & 7;
  const int b1 = b0 + 32;
  const int u0 = ublk * 8 + ul0;

  const unsigned short* xpd = xp + (size_t)dir * T_ * NROW * 64;
  const unsigned short* hc = hbuf + (size_t)dir * B_ * H_;              // buf 0
  unsigned short*       hn = hbuf + (size_t)(2 + dir) * B_ * H_;        // buf 1

  for (int s = 0; s < T_; ++s) {
    // prefetch this step's xp for my two cells (streamed from HBM)
    const unsigned short* xps = xpd + (size_t)s * NROW * 64;
    unsigned short xv0[5], xv1[5];
#pragma unroll
    for (int g = 0; g < 5; ++g) {
      xv0[g] = xps[(size_t)(g * H_ + u0) * 64 + b0];
      xv1[g] = xps[(size_t)(g * H_ + u0) * 64 + b1];
    }

    // GEMM: gates[16 batches of wv][48 rows] = h · Wh^T   (K = 512)
    f32x4 acc0 = zz, acc1 = zz, acc2 = zz;
    const unsigned short* hrow = hc + (size_t)(wv * 16 + l15) * H_ + l4 * 8;
#pragma unroll
    for (int ks = 0; ks < 16; ++ks) {
      bf16x8 a = *(const bf16x8*)(hrow + ks * 32);
      acc0 = MFMA16(a, wfrag[0][ks], acc0);
      acc1 = MFMA16(a, wfrag[1][ks], acc1);
      acc2 = MFMA16(a, wfrag[2][ks], acc2);
    }
    // dump D: row(M)=batch=(l>>4)*4+r, col(N)=gate row=l&15
#pragma unroll
    for (int rr = 0; rr < 4; ++rr) {
      int b = wv * 16 + l4 * 4 + rr;
      gate_lds[b][0 + l15]  = acc0[rr];
      gate_lds[b][16 + l15] = acc1[rr];
      gate_lds[b][32 + l15] = acc2[rr];
    }
    __syncthreads();

    // pointwise cell update for my 2 cells
    float p0 = gate_lds[b0][0 * 8 + ul0] + bf2f(xv0[0]);
    float p1 = gate_lds[b0][1 * 8 + ul0] + bf2f(xv0[1]);
    float p2 = gate_lds[b0][2 * 8 + ul0] + bf2f(xv0[2]);
    float p3 = gate_lds[b0][3 * 8 + ul0] + bf2f(xv0[3]);
    float p4 = gate_lds[b0][4 * 8 + ul0] + bf2f(xv0[4]);
    float f0 = sigm(p0), i0 = sigm(p1), o0 = sigm(p2), uu0 = sigm(p3), tk0 = tanhf(p4);
    kpst0 = uu0 * tk0 + (1.f - uu0) * kpst0;
    kst0  = f0 * kst0 + i0 * kpst0;
    float hv0 = o0 * tanhf(kst0);

    float q0 = gate_lds[b1][0 * 8 + ul0] + bf2f(xv1[0]);
    float q1 = gate_lds[b1][1 * 8 + ul0] + bf2f(xv1[1]);
    float q2 = gate_lds[b1][2 * 8 + ul0] + bf2f(xv1[2]);
    float q3 = gate_lds[b1][3 * 8 + ul0] + bf2f(xv1[3]);
    float q4 = gate_lds[b1][4 * 8 + ul0] + bf2f(xv1[4]);
    float f1 = sigm(q0), i1 = sigm(q1), o1 = sigm(q2), uu1 = sigm(q3), tk1 = tanhf(q4);
    kpst1 = uu1 * tk1 + (1.f - uu1) * kpst1;
    kst1  = f1 * kst1 + i1 * kpst1;
    float hv1 = o1 * tanhf(kst1);

    hn[b0 * H_ + u0] = f2bf(hv0);
    hn[b1 * H_ + u0] = f2bf(hv1);
    int tout = dir ? (T_ - 1 - s) : s;
    out[((size_t)b0 * T_ + tout) * (2 * H_) + dir * H_ + u0] = hv0;
    out[((size_t)b1 * T_ + tout) * (2 * H_) + dir * H_ + u0] = hv1;

    if (s + 1 < T_) grid_barrier(bar, s);

    const unsigned short* tmp = hc; hc = hn; hn = (unsigned short*)tmp;
  }
}

// ---------------- launch ----------------
extern "C" void kernel_launch(void* const* d_in, const int* in_sizes, int n_in,
                              void* d_out, int out_size, void* d_ws, size_t ws_size,
                              hipStream_t stream) {
  const float* x    = (const float*)d_in[0];
  const float* Wx_f = (const float*)d_in[1];
  const float* bx_f = (const float*)d_in[2];
  const float* Wh_f = (const float*)d_in[3];
  const float* bh_f = (const float*)d_in[4];
  const float* Wx_b = (const float*)d_in[5];
  const float* bx_b = (const float*)d_in[6];
  const float* Wh_b = (const float*)d_in[7];
  const float* bh_b = (const float*)d_in[8];
  float* out = (float*)d_out;

  if (ws_size < WS_NEED) {
    k_sentinel<<<(out_size + 255) / 256, 256, 0, stream>>>(out, out_size);
    return;
  }

  char* ws = (char*)d_ws;
  unsigned short* xp    = (unsigned short*)(ws + OFF_XP);
  unsigned short* xb    = (unsigned short*)(ws + OFF_XB);
  unsigned short* W2x   = (unsigned short*)(ws + OFF_W2X);
  unsigned short* W2h   = (unsigned short*)(ws + OFF_W2H);
  float*          bias2 = (float*)(ws + OFF_BIAS);
  unsigned short* hbuf  = (unsigned short*)(ws + OFF_HB);
  unsigned*       bar   = (unsigned*)(ws + OFF_BAR);

  k_cvt_weights<<<(2 * NROW * KD) / 256, 256, 0, stream>>>(
      Wx_f, Wh_f, Wx_b, Wh_b, bx_f, bh_f, bx_b, bh_b, W2x, W2h, bias2);
  k_cvt_x<<<(B_ * T_ * I_) / 256, 256, 0, stream>>>(x, xb);
  k_zero_h<<<(2 * 2 * B_ * H_) / 256, 256, 0, stream>>>(hbuf, bar);
  k_gemm_xp<<<2 * 20 * 256, 256, 0, stream>>>(W2x, xb, bias2, xp);
  k_recurrent<<<NBLK_REC, 256, 0, stream>>>(W2h, xp, hbuf, out, bar);
}

// Round 3
// 5509.224 us; speedup vs baseline: 1.2437x; 1.2437x over previous
//
#include <hip/hip_runtime.h>
#include <hip/hip_bf16.h>

// Problem constants
#define B_   64
#define T_   512
#define I_   512
#define H_   512
#define G_   5
#define NROW 2560   // G*H gate rows per direction
#define KD   512    // K depth (I or H)
#define NBLK_REC 128

typedef __attribute__((ext_vector_type(8))) __bf16 bf16x8;
typedef __attribute__((ext_vector_type(4))) float  f32x4;
typedef __attribute__((ext_vector_type(2))) unsigned long long u64x2;
typedef unsigned long long u64;

#define MFMA16(A, Bf, C) __builtin_amdgcn_mfma_f32_16x16x32_bf16(A, Bf, C, 0, 0, 0)

__device__ __forceinline__ unsigned short f2bf(float f) {
  unsigned u = __builtin_bit_cast(unsigned, f);
  u = (u + 0x7fffu + ((u >> 16) & 1u)) >> 16;   // RNE
  return (unsigned short)u;
}
__device__ __forceinline__ float bf2f(unsigned short s) {
  unsigned u = ((unsigned)s) << 16;
  return __builtin_bit_cast(float, u);
}
__device__ __forceinline__ float sigm(float x) { return 1.f / (1.f + __expf(-x)); }
// tanh via exp2-free fast path: tanh(x) = 1 - 2/(e^{2x}+1)
__device__ __forceinline__ float tanh_fast(float x) {
  return 1.f - 2.f / (__expf(2.f * x) + 1.f);
}

// ---------------- ws layout (bytes) ----------------
#define OFF_XP   ((size_t)0)
#define OFF_XB   ((size_t)335544320)
#define OFF_W2X  ((size_t)369098752)
#define OFF_W2H  ((size_t)374341632)
#define OFF_BIAS ((size_t)379584512)
#define OFF_HB   ((size_t)379604992)
#define OFF_BAR  ((size_t)379867136)
#define WS_NEED  ((size_t)379871232)

// ---------------- sentinel (ws too small) ----------------
__global__ void k_sentinel(float* out, int n) {
  int i = blockIdx.x * 256 + threadIdx.x;
  if (i < n) out[i] = 10000.0f;
}

// ---------------- converts ----------------
__global__ void k_cvt_weights(const float* __restrict__ Wx_f, const float* __restrict__ Wh_f,
                              const float* __restrict__ Wx_b, const float* __restrict__ Wh_b,
                              const float* __restrict__ bx_f, const float* __restrict__ bh_f,
                              const float* __restrict__ bx_b, const float* __restrict__ bh_b,
                              unsigned short* __restrict__ W2x, unsigned short* __restrict__ W2h,
                              float* __restrict__ bias2) {
  int idx = blockIdx.x * 256 + threadIdx.x;       // exactly 2*NROW*KD threads
  int dir = idx / (NROW * KD);
  int r   = idx % (NROW * KD);
  W2x[idx] = f2bf(dir ? Wx_b[r] : Wx_f[r]);
  W2h[idx] = f2bf(dir ? Wh_b[r] : Wh_f[r]);
  if (idx < 2 * NROW) {
    int d2 = idx / NROW, n = idx % NROW;
    bias2[idx] = d2 ? (bx_b[n] + bh_b[n]) : (bx_f[n] + bh_f[n]);
  }
}

__global__ void k_cvt_x(const float* __restrict__ x, unsigned short* __restrict__ xb) {
  int idx = blockIdx.x * 256 + threadIdx.x;       // exactly B*T*I threads
  xb[idx] = f2bf(x[idx]);
}

__global__ void k_zero_h(unsigned short* __restrict__ hb, unsigned* __restrict__ bar) {
  int idx = blockIdx.x * 256 + threadIdx.x;       // exactly 2*2*B*H threads
  hb[idx] = 0;
  if (idx < 1024) bar[idx] = 0;
}

// ---------------- phase 1: xp = Wx · x^T (+bias), both dirs ----------------
__global__ __launch_bounds__(256) void k_gemm_xp(
    const unsigned short* __restrict__ W2x,   // [2][NROW][KD]
    const unsigned short* __restrict__ xb,    // [B][T][I]
    const float* __restrict__ bias2,          // [2][NROW]
    unsigned short* __restrict__ xp)          // [2][T][NROW][B]
{
  const int tid = threadIdx.x;
  const int lane = tid & 63, wv = tid >> 6;
  int bz = blockIdx.x;
  const int dir = bz / (20 * 256); bz %= (20 * 256);
  const int nblk = bz / 256, mblk = bz % 256;
  const int n0 = nblk * 128, m0 = mblk * 128;
  const int l15 = lane & 15, l4 = lane >> 4;
  const int nh = wv >> 1, mh = wv & 1;

  __shared__ unsigned short Al[128 * 72];
  __shared__ unsigned short Bl[128 * 72];

  const unsigned short* Wd = W2x + (size_t)dir * NROW * KD;

  f32x4 acc[4][4];
  f32x4 zz = {0.f, 0.f, 0.f, 0.f};
#pragma unroll
  for (int i = 0; i < 4; ++i)
#pragma unroll
    for (int j = 0; j < 4; ++j) acc[i][j] = zz;

  for (int k0 = 0; k0 < KD; k0 += 64) {
#pragma unroll
    for (int j = 0; j < 4; ++j) {
      int sg = j * 256 + tid;
      int row = sg >> 3, ko = (sg & 7) * 8;
      bf16x8 va = *(const bf16x8*)(Wd + (size_t)(n0 + row) * KD + k0 + ko);
      *(bf16x8*)(Al + row * 72 + ko) = va;
      int m = m0 + row;
      int ss = m >> 6, b = m & 63;
      int trow = dir ? (T_ - 1 - ss) : ss;
      bf16x8 vb = *(const bf16x8*)(xb + ((size_t)b * T_ + trow) * I_ + k0 + ko);
      *(bf16x8*)(Bl + row * 72 + ko) = vb;
    }
    __syncthreads();
#pragma unroll
    for (int kk = 0; kk < 2; ++kk) {
      bf16x8 af[4], bfr[4];
#pragma unroll
      for (int f = 0; f < 4; ++f) {
        af[f]  = *(const bf16x8*)(Al + (nh * 64 + f * 16 + l15) * 72 + kk * 32 + l4 * 8);
        bfr[f] = *(const bf16x8*)(Bl + (mh * 64 + f * 16 + l15) * 72 + kk * 32 + l4 * 8);
      }
#pragma unroll
      for (int fi = 0; fi < 4; ++fi)
#pragma unroll
        for (int fj = 0; fj < 4; ++fj)
          acc[fi][fj] = MFMA16(af[fi], bfr[fj], acc[fi][fj]);
    }
    __syncthreads();
  }

#pragma unroll
  for (int fi = 0; fi < 4; ++fi) {
#pragma unroll
    for (int fj = 0; fj < 4; ++fj) {
#pragma unroll
      for (int r = 0; r < 4; ++r) {
        int n = n0 + nh * 64 + fi * 16 + l4 * 4 + r;
        int m = m0 + mh * 64 + fj * 16 + l15;
        int ss = m >> 6, b = m & 63;
        float v = acc[fi][fj][r] + bias2[dir * NROW + n];
        xp[(((size_t)dir * T_ + ss) * NROW + n) * 64 + b] = f2bf(v);
      }
    }
  }
}

// ---------------- phase 2: persistent recurrent kernel ----------------
// 128 blocks (dir = bid&1, ublk = bid>>1 owns 8 units), 256 threads = 4 waves.
// h exchange: agent-scope relaxed atomic stores/loads (L2-bypass, no fences).
// Step handoff: per-wave epoch flags (512 disjoint words), wave-parallel poll.
__global__ __launch_bounds__(256, 1) void k_recurrent(
    const unsigned short* __restrict__ W2h,  // [2][NROW][KD]
    const unsigned short* __restrict__ xp,   // [2][T][NROW][B]
    unsigned short* __restrict__ hbuf,       // [2][2][B][H]
    float* __restrict__ out,                 // [B][T][2H]
    unsigned* __restrict__ bar)              // [2][256] per-wave epoch flags
{
  const int tid = threadIdx.x;
  const int lane = tid & 63, wv = tid >> 6;
  const int bid = blockIdx.x;
  const int dir = bid & 1;
  const int ublk = bid >> 1;
  const int l15 = lane & 15, l4 = lane >> 4;

  __shared__ float gate_lds[64][52];
  __shared__ unsigned short xp_lds[5][8][72];

  f32x4 zz = {0.f, 0.f, 0.f, 0.f};
  const bf16x8 zfrag = __builtin_bit_cast(bf16x8, zz);

  // recurrent-weight fragments resident in registers for all 512 steps
  bf16x8 wfrag[3][16];
#pragma unroll
  for (int nt = 0; nt < 3; ++nt) {
    int r = nt * 16 + l15;
#pragma unroll
    for (int ks = 0; ks < 16; ++ks) {
      if (r < 40) {
        int g = r >> 3, ul = r & 7;
        const unsigned short* wrow =
            W2h + ((size_t)dir * NROW + g * H_ + ublk * 8 + ul) * KD;
        wfrag[nt][ks] = *(const bf16x8*)(wrow + ks * 32 + l4 * 8);
      } else {
        wfrag[nt][ks] = zfrag;
      }
    }
  }

  // cell ownership: thread -> (b = tid>>2, units u0..u0+1 with u0 = ublk*8 + (tid&3)*2)
  const int bb  = tid >> 2;
  const int up  = (tid & 3) * 2;
  const int ubase = ublk * 8 + up;
  float kst0 = 0.f, kpst0 = 0.f, kst1 = 0.f, kpst1 = 0.f;

  const unsigned short* xpd = xp + (size_t)dir * T_ * NROW * 64;
  const unsigned short* hc = hbuf + (size_t)dir * B_ * H_;              // buf 0
  unsigned short*       hn = hbuf + (size_t)(2 + dir) * B_ * H_;        // buf 1
  unsigned* flagsd = bar + dir * 256;
  const int myflag = ublk * 4 + wv;

  // stage xp regs for step 0 (coalesced u32 cooperative loads, 1KB per gate region)
  unsigned xr0, xr1, xr2, xr3, xr4;
  {
    const unsigned short* base = xpd + (size_t)(0) * NROW * 64 + (size_t)ublk * 8 * 64;
    xr0 = ((const unsigned*)(base + 0 * H_ * 64))[tid];
    xr1 = ((const unsigned*)(base + 1 * H_ * 64))[tid];
    xr2 = ((const unsigned*)(base + 2 * H_ * 64))[tid];
    xr3 = ((const unsigned*)(base + 3 * H_ * 64))[tid];
    xr4 = ((const unsigned*)(base + 4 * H_ * 64))[tid];
  }
  const int xu = tid >> 5, xb2 = (tid & 31) * 2;

  for (int s = 0; s < T_; ++s) {
    // commit staged xp for this step into LDS (safe: all waves passed flag-wait s-1)
    *(unsigned*)&xp_lds[0][xu][xb2] = xr0;
    *(unsigned*)&xp_lds[1][xu][xb2] = xr1;
    *(unsigned*)&xp_lds[2][xu][xb2] = xr2;
    *(unsigned*)&xp_lds[3][xu][xb2] = xr3;
    *(unsigned*)&xp_lds[4][xu][xb2] = xr4;

    // h loads: L2-bypassing u64 atomic loads (fresh cross-XCD data)
    const u64* hq = (const u64*)(hc + (size_t)(wv * 16 + l15) * H_ + l4 * 8);
    u64 hlo[16], hhi[16];
#pragma unroll
    for (int ks = 0; ks < 16; ++ks) {
      hlo[ks] = __hip_atomic_load(hq + ks * 8,     __ATOMIC_RELAXED, __HIP_MEMORY_SCOPE_AGENT);
      hhi[ks] = __hip_atomic_load(hq + ks * 8 + 1, __ATOMIC_RELAXED, __HIP_MEMORY_SCOPE_AGENT);
    }
    f32x4 acc0 = zz, acc1 = zz, acc2 = zz;
#pragma unroll
    for (int ks = 0; ks < 16; ++ks) {
      u64x2 t2 = {hlo[ks], hhi[ks]};
      bf16x8 a = __builtin_bit_cast(bf16x8, t2);
      acc0 = MFMA16(a, wfrag[0][ks], acc0);
      acc1 = MFMA16(a, wfrag[1][ks], acc1);
      acc2 = MFMA16(a, wfrag[2][ks], acc2);
    }
    // dump D: row(M)=batch=(l>>4)*4+r, col(N)=gate row=l&15
#pragma unroll
    for (int rr = 0; rr < 4; ++rr) {
      int b = wv * 16 + l4 * 4 + rr;
      gate_lds[b][0 + l15]  = acc0[rr];
      gate_lds[b][16 + l15] = acc1[rr];
      gate_lds[b][32 + l15] = acc2[rr];
    }
    __syncthreads();

    // pointwise for cells (bb, ubase) and (bb, ubase+1)
    float p0 = gate_lds[bb][0 * 8 + up]     + bf2f(xp_lds[0][up][bb]);
    float p1 = gate_lds[bb][1 * 8 + up]     + bf2f(xp_lds[1][up][bb]);
    float p2 = gate_lds[bb][2 * 8 + up]     + bf2f(xp_lds[2][up][bb]);
    float p3 = gate_lds[bb][3 * 8 + up]     + bf2f(xp_lds[3][up][bb]);
    float p4 = gate_lds[bb][4 * 8 + up]     + bf2f(xp_lds[4][up][bb]);
    float q0 = gate_lds[bb][0 * 8 + up + 1] + bf2f(xp_lds[0][up + 1][bb]);
    float q1 = gate_lds[bb][1 * 8 + up + 1] + bf2f(xp_lds[1][up + 1][bb]);
    float q2 = gate_lds[bb][2 * 8 + up + 1] + bf2f(xp_lds[2][up + 1][bb]);
    float q3 = gate_lds[bb][3 * 8 + up + 1] + bf2f(xp_lds[3][up + 1][bb]);
    float q4 = gate_lds[bb][4 * 8 + up + 1] + bf2f(xp_lds[4][up + 1][bb]);

    float f0 = sigm(p0), i0 = sigm(p1), o0 = sigm(p2), uu0 = sigm(p3), tk0 = tanh_fast(p4);
    kpst0 = uu0 * tk0 + (1.f - uu0) * kpst0;
    kst0  = f0 * kst0 + i0 * kpst0;
    float hv0 = o0 * tanh_fast(kst0);

    float f1 = sigm(q0), i1 = sigm(q1), o1 = sigm(q2), uu1 = sigm(q3), tk1 = tanh_fast(q4);
    kpst1 = uu1 * tk1 + (1.f - uu1) * kpst1;
    kst1  = f1 * kst1 + i1 * kpst1;
    float hv1 = o1 * tanh_fast(kst1);

    // publish h (write-through, L2-bypass) + write out (plain cached)
    unsigned hw = (unsigned)f2bf(hv0) | ((unsigned)f2bf(hv1) << 16);
    __hip_atomic_store((unsigned*)(hn + (size_t)bb * H_ + ubase), hw,
                       __ATOMIC_RELAXED, __HIP_MEMORY_SCOPE_AGENT);
    int tout = dir ? (T_ - 1 - s) : s;
    float2 ov = {hv0, hv1};
    *(float2*)&out[((size_t)bb * T_ + tout) * (2 * H_) + dir * H_ + ubase] = ov;

    if (s + 1 < T_) {
      asm volatile("" ::: "memory");   // pin: stores issue before prefetch loads
      // prefetch next step's xp into regs (latency hides under flag wait)
      const unsigned short* nbase = xpd + (size_t)(s + 1) * NROW * 64 + (size_t)ublk * 8 * 64;
      xr0 = ((const unsigned*)(nbase + 0 * H_ * 64))[tid];
      xr1 = ((const unsigned*)(nbase + 1 * H_ * 64))[tid];
      xr2 = ((const unsigned*)(nbase + 2 * H_ * 64))[tid];
      xr3 = ((const unsigned*)(nbase + 3 * H_ * 64))[tid];
      xr4 = ((const unsigned*)(nbase + 4 * H_ * 64))[tid];
      // drain all vmem EXCEPT the 5 newest (the prefetch loads): h/out stores now in L3
      asm volatile("s_waitcnt vmcnt(5)" ::: "memory");
      if (lane == 0)
        __hip_atomic_store(&flagsd[myflag], (unsigned)(s + 1),
                           __ATOMIC_RELAXED, __HIP_MEMORY_SCOPE_AGENT);
      // wave-parallel poll: 64 lanes x 4 flags = all 256 waves of this direction
      unsigned tgt = (unsigned)(s + 1);
      unsigned v;
      do {
        unsigned a0 = __hip_atomic_load(&flagsd[lane],       __ATOMIC_RELAXED, __HIP_MEMORY_SCOPE_AGENT);
        unsigned a1 = __hip_atomic_load(&flagsd[lane + 64],  __ATOMIC_RELAXED, __HIP_MEMORY_SCOPE_AGENT);
        unsigned a2 = __hip_atomic_load(&flagsd[lane + 128], __ATOMIC_RELAXED, __HIP_MEMORY_SCOPE_AGENT);
        unsigned a3 = __hip_atomic_load(&flagsd[lane + 192], __ATOMIC_RELAXED, __HIP_MEMORY_SCOPE_AGENT);
        unsigned m0 = a0 < a1 ? a0 : a1;
        unsigned m1 = a2 < a3 ? a2 : a3;
        v = m0 < m1 ? m0 : m1;
      } while (__any(v < tgt));
      asm volatile("" ::: "memory");   // no motion of next-step loads above the spin
    }

    const unsigned short* tmp = hc; hc = hn; hn = (unsigned short*)tmp;
  }
}

// ---------------- launch ----------------
extern "C" void kernel_launch(void* const* d_in, const int* in_sizes, int n_in,
                              void* d_out, int out_size, void* d_ws, size_t ws_size,
                              hipStream_t stream) {
  const float* x    = (const float*)d_in[0];
  const float* Wx_f = (const float*)d_in[1];
  const float* bx_f = (const float*)d_in[2];
  const float* Wh_f = (const float*)d_in[3];
  const float* bh_f = (const float*)d_in[4];
  const float* Wx_b = (const float*)d_in[5];
  const float* bx_b = (const float*)d_in[6];
  const float* Wh_b = (const float*)d_in[7];
  const float* bh_b = (const float*)d_in[8];
  float* out = (float*)d_out;

  if (ws_size < WS_NEED) {
    k_sentinel<<<(out_size + 255) / 256, 256, 0, stream>>>(out, out_size);
    return;
  }

  char* ws = (char*)d_ws;
  unsigned short* xp    = (unsigned short*)(ws + OFF_XP);
  unsigned short* xb    = (unsigned short*)(ws + OFF_XB);
  unsigned short* W2x   = (unsigned short*)(ws + OFF_W2X);
  unsigned short* W2h   = (unsigned short*)(ws + OFF_W2H);
  float*          bias2 = (float*)(ws + OFF_BIAS);
  unsigned short* hbuf  = (unsigned short*)(ws + OFF_HB);
  unsigned*       bar   = (unsigned*)(ws + OFF_BAR);

  k_cvt_weights<<<(2 * NROW * KD) / 256, 256, 0, stream>>>(
      Wx_f, Wh_f, Wx_b, Wh_b, bx_f, bh_f, bx_b, bh_b, W2x, W2h, bias2);
  k_cvt_x<<<(B_ * T_ * I_) / 256, 256, 0, stream>>>(x, xb);
  k_zero_h<<<(2 * 2 * B_ * H_) / 256, 256, 0, stream>>>(hbuf, bar);
  k_gemm_xp<<<2 * 20 * 256, 256, 0, stream>>>(W2x, xb, bias2, xp);
  k_recurrent<<<NBLK_REC, 256, 0, stream>>>(W2h, xp, hbuf, out, bar);
}

// Round 4
// 4404.255 us; speedup vs baseline: 1.5558x; 1.2509x over previous
//
#include <hip/hip_runtime.h>
#include <hip/hip_bf16.h>

// Problem constants
#define B_   64
#define T_   512
#define I_   512
#define H_   512
#define G_   5
#define NROW 2560   // G*H gate rows per direction
#define KD   512    // K depth (I or H)
#define NBLK_REC 128

typedef __attribute__((ext_vector_type(8))) __bf16 bf16x8;
typedef __attribute__((ext_vector_type(4))) float  f32x4;
typedef __attribute__((ext_vector_type(2))) unsigned long long u64x2;
typedef unsigned long long u64;

#define MFMA16(A, Bf, C) __builtin_amdgcn_mfma_f32_16x16x32_bf16(A, Bf, C, 0, 0, 0)

__device__ __forceinline__ unsigned short f2bf(float f) {
  unsigned u = __builtin_bit_cast(unsigned, f);
  u = (u + 0x7fffu + ((u >> 16) & 1u)) >> 16;   // RNE
  return (unsigned short)u;
}
__device__ __forceinline__ float bf2f(unsigned short s) {
  unsigned u = ((unsigned)s) << 16;
  return __builtin_bit_cast(float, u);
}
__device__ __forceinline__ float sigm(float x) { return 1.f / (1.f + __expf(-x)); }
__device__ __forceinline__ float tanh_fast(float x) {
  return 1.f - 2.f / (__expf(2.f * x) + 1.f);
}

// ---------------- ws layout (bytes) ----------------
#define OFF_XP   ((size_t)0)
#define OFF_XB   ((size_t)335544320)
#define OFF_W2X  ((size_t)369098752)
#define OFF_W2H  ((size_t)374341632)
#define OFF_BIAS ((size_t)379584512)
#define OFF_HB   ((size_t)379604992)
#define OFF_BAR  ((size_t)379867136)
#define WS_NEED  ((size_t)379871232)

// ---------------- sentinel (ws too small) ----------------
__global__ void k_sentinel(float* out, int n) {
  int i = blockIdx.x * 256 + threadIdx.x;
  if (i < n) out[i] = 10000.0f;
}

// ---------------- converts ----------------
__global__ void k_cvt_weights(const float* __restrict__ Wx_f, const float* __restrict__ Wh_f,
                              const float* __restrict__ Wx_b, const float* __restrict__ Wh_b,
                              const float* __restrict__ bx_f, const float* __restrict__ bh_f,
                              const float* __restrict__ bx_b, const float* __restrict__ bh_b,
                              unsigned short* __restrict__ W2x, unsigned short* __restrict__ W2h,
                              float* __restrict__ bias2) {
  int idx = blockIdx.x * 256 + threadIdx.x;       // exactly 2*NROW*KD threads
  int dir = idx / (NROW * KD);
  int r   = idx % (NROW * KD);
  W2x[idx] = f2bf(dir ? Wx_b[r] : Wx_f[r]);
  W2h[idx] = f2bf(dir ? Wh_b[r] : Wh_f[r]);
  if (idx < 2 * NROW) {
    int d2 = idx / NROW, n = idx % NROW;
    bias2[idx] = d2 ? (bx_b[n] + bh_b[n]) : (bx_f[n] + bh_f[n]);
  }
}

__global__ void k_cvt_x(const float* __restrict__ x, unsigned short* __restrict__ xb) {
  int idx = blockIdx.x * 256 + threadIdx.x;       // exactly B*T*I threads
  xb[idx] = f2bf(x[idx]);
}

__global__ void k_zero_h(unsigned short* __restrict__ hb, unsigned* __restrict__ bar) {
  int idx = blockIdx.x * 256 + threadIdx.x;       // exactly 2*2*B*H threads
  hb[idx] = 0;
  if (idx < 1024) bar[idx] = 0;
}

// ---------------- phase 1: xp = Wx · x^T (+bias), both dirs ----------------
__global__ __launch_bounds__(256) void k_gemm_xp(
    const unsigned short* __restrict__ W2x,   // [2][NROW][KD]
    const unsigned short* __restrict__ xb,    // [B][T][I]
    const float* __restrict__ bias2,          // [2][NROW]
    unsigned short* __restrict__ xp)          // [2][T][NROW][B]
{
  const int tid = threadIdx.x;
  const int lane = tid & 63, wv = tid >> 6;
  int bz = blockIdx.x;
  const int dir = bz / (20 * 256); bz %= (20 * 256);
  const int nblk = bz / 256, mblk = bz % 256;
  const int n0 = nblk * 128, m0 = mblk * 128;
  const int l15 = lane & 15, l4 = lane >> 4;
  const int nh = wv >> 1, mh = wv & 1;

  __shared__ unsigned short Al[128 * 72];
  __shared__ unsigned short Bl[128 * 72];

  const unsigned short* Wd = W2x + (size_t)dir * NROW * KD;

  f32x4 acc[4][4];
  f32x4 zz = {0.f, 0.f, 0.f, 0.f};
#pragma unroll
  for (int i = 0; i < 4; ++i)
#pragma unroll
    for (int j = 0; j < 4; ++j) acc[i][j] = zz;

  for (int k0 = 0; k0 < KD; k0 += 64) {
#pragma unroll
    for (int j = 0; j < 4; ++j) {
      int sg = j * 256 + tid;
      int row = sg >> 3, ko = (sg & 7) * 8;
      bf16x8 va = *(const bf16x8*)(Wd + (size_t)(n0 + row) * KD + k0 + ko);
      *(bf16x8*)(Al + row * 72 + ko) = va;
      int m = m0 + row;
      int ss = m >> 6, b = m & 63;
      int trow = dir ? (T_ - 1 - ss) : ss;
      bf16x8 vb = *(const bf16x8*)(xb + ((size_t)b * T_ + trow) * I_ + k0 + ko);
      *(bf16x8*)(Bl + row * 72 + ko) = vb;
    }
    __syncthreads();
#pragma unroll
    for (int kk = 0; kk < 2; ++kk) {
      bf16x8 af[4], bfr[4];
#pragma unroll
      for (int f = 0; f < 4; ++f) {
        af[f]  = *(const bf16x8*)(Al + (nh * 64 + f * 16 + l15) * 72 + kk * 32 + l4 * 8);
        bfr[f] = *(const bf16x8*)(Bl + (mh * 64 + f * 16 + l15) * 72 + kk * 32 + l4 * 8);
      }
#pragma unroll
      for (int fi = 0; fi < 4; ++fi)
#pragma unroll
        for (int fj = 0; fj < 4; ++fj)
          acc[fi][fj] = MFMA16(af[fi], bfr[fj], acc[fi][fj]);
    }
    __syncthreads();
  }

#pragma unroll
  for (int fi = 0; fi < 4; ++fi) {
#pragma unroll
    for (int fj = 0; fj < 4; ++fj) {
#pragma unroll
      for (int r = 0; r < 4; ++r) {
        int n = n0 + nh * 64 + fi * 16 + l4 * 4 + r;
        int m = m0 + mh * 64 + fj * 16 + l15;
        int ss = m >> 6, b = m & 63;
        float v = acc[fi][fj][r] + bias2[dir * NROW + n];
        xp[(((size_t)dir * T_ + ss) * NROW + n) * 64 + b] = f2bf(v);
      }
    }
  }
}

// ---------------- phase 2: persistent recurrent kernel ----------------
// 128 blocks (dir = bid&1, ublk = bid>>1 owns 8 units), 256 threads = 4 waves.
// h exchange: agent-scope relaxed atomic stores/loads (L3, no fences).
// Step handoff: per-BLOCK epoch flags; wave 0 polls (throttled), others wait
// at __syncthreads. Each wave drains its h-store (vmcnt(0)) before arrival.
__global__ __launch_bounds__(256, 1) void k_recurrent(
    const unsigned short* __restrict__ W2h,  // [2][NROW][KD]
    const unsigned short* __restrict__ xp,   // [2][T][NROW][B]
    unsigned short* __restrict__ hbuf,       // [2][2][B][H]
    float* __restrict__ out,                 // [B][T][2H]
    unsigned* __restrict__ bar)              // [2][64] per-block epoch flags
{
  const int tid = threadIdx.x;
  const int lane = tid & 63, wv = tid >> 6;
  const int bid = blockIdx.x;
  const int dir = bid & 1;
  const int ublk = bid >> 1;
  const int l15 = lane & 15, l4 = lane >> 4;

  __shared__ float gate_lds[64][52];
  __shared__ unsigned short xp_lds[5][8][72];

  f32x4 zz = {0.f, 0.f, 0.f, 0.f};
  const bf16x8 zfrag = __builtin_bit_cast(bf16x8, zz);

  // recurrent-weight fragments resident in registers for all 512 steps
  bf16x8 wfrag[3][16];
#pragma unroll
  for (int nt = 0; nt < 3; ++nt) {
    int r = nt * 16 + l15;
#pragma unroll
    for (int ks = 0; ks < 16; ++ks) {
      if (r < 40) {
        int g = r >> 3, ul = r & 7;
        const unsigned short* wrow =
            W2h + ((size_t)dir * NROW + g * H_ + ublk * 8 + ul) * KD;
        wfrag[nt][ks] = *(const bf16x8*)(wrow + ks * 32 + l4 * 8);
      } else {
        wfrag[nt][ks] = zfrag;
      }
    }
  }

  // cell ownership: thread -> (b = tid>>2, units u0..u0+1 with u0 = ublk*8 + (tid&3)*2)
  const int bb  = tid >> 2;
  const int up  = (tid & 3) * 2;
  const int ubase = ublk * 8 + up;
  float kst0 = 0.f, kpst0 = 0.f, kst1 = 0.f, kpst1 = 0.f;

  const unsigned short* xpd = xp + (size_t)dir * T_ * NROW * 64;
  const unsigned short* hc = hbuf + (size_t)dir * B_ * H_;              // buf 0
  unsigned short*       hn = hbuf + (size_t)(2 + dir) * B_ * H_;        // buf 1
  unsigned* flagsd = bar + dir * 64;

  // stage xp regs for step 0 (coalesced u32 cooperative loads)
  unsigned xr0, xr1, xr2, xr3, xr4;
  {
    const unsigned short* base = xpd + (size_t)ublk * 8 * 64;
    xr0 = ((const unsigned*)(base + 0 * H_ * 64))[tid];
    xr1 = ((const unsigned*)(base + 1 * H_ * 64))[tid];
    xr2 = ((const unsigned*)(base + 2 * H_ * 64))[tid];
    xr3 = ((const unsigned*)(base + 3 * H_ * 64))[tid];
    xr4 = ((const unsigned*)(base + 4 * H_ * 64))[tid];
  }
  const int xu = tid >> 5, xb2 = (tid & 31) * 2;

  for (int s = 0; s < T_; ++s) {
    // commit staged xp for this step into LDS
    *(unsigned*)&xp_lds[0][xu][xb2] = xr0;
    *(unsigned*)&xp_lds[1][xu][xb2] = xr1;
    *(unsigned*)&xp_lds[2][xu][xb2] = xr2;
    *(unsigned*)&xp_lds[3][xu][xb2] = xr3;
    *(unsigned*)&xp_lds[4][xu][xb2] = xr4;

    // h loads: L2-bypassing u64 atomic loads (fresh cross-XCD data)
    const u64* hq = (const u64*)(hc + (size_t)(wv * 16 + l15) * H_ + l4 * 8);
    u64 hlo[16], hhi[16];
#pragma unroll
    for (int ks = 0; ks < 16; ++ks) {
      hlo[ks] = __hip_atomic_load(hq + ks * 8,     __ATOMIC_RELAXED, __HIP_MEMORY_SCOPE_AGENT);
      hhi[ks] = __hip_atomic_load(hq + ks * 8 + 1, __ATOMIC_RELAXED, __HIP_MEMORY_SCOPE_AGENT);
    }
    // 6 accumulator chains (depth 8 each) to cut serial MFMA latency
    f32x4 a0a = zz, a0b = zz, a1a = zz, a1b = zz, a2a = zz, a2b = zz;
#pragma unroll
    for (int ks = 0; ks < 8; ++ks) {
      u64x2 t2 = {hlo[ks], hhi[ks]};
      bf16x8 a = __builtin_bit_cast(bf16x8, t2);
      a0a = MFMA16(a, wfrag[0][ks], a0a);
      a1a = MFMA16(a, wfrag[1][ks], a1a);
      a2a = MFMA16(a, wfrag[2][ks], a2a);
    }
#pragma unroll
    for (int ks = 8; ks < 16; ++ks) {
      u64x2 t2 = {hlo[ks], hhi[ks]};
      bf16x8 a = __builtin_bit_cast(bf16x8, t2);
      a0b = MFMA16(a, wfrag[0][ks], a0b);
      a1b = MFMA16(a, wfrag[1][ks], a1b);
      a2b = MFMA16(a, wfrag[2][ks], a2b);
    }
    f32x4 acc0 = a0a + a0b, acc1 = a1a + a1b, acc2 = a2a + a2b;

    // dump D: row(M)=batch=(l>>4)*4+r, col(N)=gate row=l&15
#pragma unroll
    for (int rr = 0; rr < 4; ++rr) {
      int b = wv * 16 + l4 * 4 + rr;
      gate_lds[b][0 + l15]  = acc0[rr];
      gate_lds[b][16 + l15] = acc1[rr];
      gate_lds[b][32 + l15] = acc2[rr];
    }
    __syncthreads();

    // pointwise for cells (bb, ubase) and (bb, ubase+1)
    float p0 = gate_lds[bb][0 * 8 + up]     + bf2f(xp_lds[0][up][bb]);
    float p1 = gate_lds[bb][1 * 8 + up]     + bf2f(xp_lds[1][up][bb]);
    float p2 = gate_lds[bb][2 * 8 + up]     + bf2f(xp_lds[2][up][bb]);
    float p3 = gate_lds[bb][3 * 8 + up]     + bf2f(xp_lds[3][up][bb]);
    float p4 = gate_lds[bb][4 * 8 + up]     + bf2f(xp_lds[4][up][bb]);
    float q0 = gate_lds[bb][0 * 8 + up + 1] + bf2f(xp_lds[0][up + 1][bb]);
    float q1 = gate_lds[bb][1 * 8 + up + 1] + bf2f(xp_lds[1][up + 1][bb]);
    float q2 = gate_lds[bb][2 * 8 + up + 1] + bf2f(xp_lds[2][up + 1][bb]);
    float q3 = gate_lds[bb][3 * 8 + up + 1] + bf2f(xp_lds[3][up + 1][bb]);
    float q4 = gate_lds[bb][4 * 8 + up + 1] + bf2f(xp_lds[4][up + 1][bb]);

    float f0 = sigm(p0), i0 = sigm(p1), o0 = sigm(p2), uu0 = sigm(p3), tk0 = tanh_fast(p4);
    kpst0 = uu0 * tk0 + (1.f - uu0) * kpst0;
    kst0  = f0 * kst0 + i0 * kpst0;
    float hv0 = o0 * tanh_fast(kst0);

    float f1 = sigm(q0), i1 = sigm(q1), o1 = sigm(q2), uu1 = sigm(q3), tk1 = tanh_fast(q4);
    kpst1 = uu1 * tk1 + (1.f - uu1) * kpst1;
    kst1  = f1 * kst1 + i1 * kpst1;
    float hv1 = o1 * tanh_fast(kst1);

    // publish h (agent-scope, goes to L3) — FIRST, it is the critical path
    unsigned hw = (unsigned)f2bf(hv0) | ((unsigned)f2bf(hv1) << 16);
    __hip_atomic_store((unsigned*)(hn + (size_t)bb * H_ + ubase), hw,
                       __ATOMIC_RELAXED, __HIP_MEMORY_SCOPE_AGENT);

    int tout = dir ? (T_ - 1 - s) : s;
    if (s + 1 < T_) {
      // drain the h store (only outstanding vmem op) before signaling
      asm volatile("s_waitcnt vmcnt(0)" ::: "memory");
      // off-critical-path work: out store + next xp prefetch (overlap the poll)
      float2 ov = {hv0, hv1};
      *(float2*)&out[((size_t)bb * T_ + tout) * (2 * H_) + dir * H_ + ubase] = ov;
      const unsigned short* nbase = xpd + (size_t)(s + 1) * NROW * 64 + (size_t)ublk * 8 * 64;
      xr0 = ((const unsigned*)(nbase + 0 * H_ * 64))[tid];
      xr1 = ((const unsigned*)(nbase + 1 * H_ * 64))[tid];
      xr2 = ((const unsigned*)(nbase + 2 * H_ * 64))[tid];
      xr3 = ((const unsigned*)(nbase + 3 * H_ * 64))[tid];
      xr4 = ((const unsigned*)(nbase + 4 * H_ * 64))[tid];

      __syncthreads();                       // all waves' h stores are drained
      if (wv == 0) {
        if (lane == 0)
          __hip_atomic_store(&flagsd[ublk], (unsigned)(s + 1),
                             __ATOMIC_RELAXED, __HIP_MEMORY_SCOPE_AGENT);
        unsigned tgt = (unsigned)(s + 1);
        for (;;) {
          unsigned v = __hip_atomic_load(&flagsd[lane],
                                         __ATOMIC_RELAXED, __HIP_MEMORY_SCOPE_AGENT);
          if (!__any(v < tgt)) break;
          __builtin_amdgcn_s_sleep(1);       // throttle poll: ~64 cy between rounds
        }
      }
      __syncthreads();                       // release all waves
    } else {
      float2 ov = {hv0, hv1};
      *(float2*)&out[((size_t)bb * T_ + tout) * (2 * H_) + dir * H_ + ubase] = ov;
    }

    const unsigned short* tmp = hc; hc = hn; hn = (unsigned short*)tmp;
  }
}

// ---------------- launch ----------------
extern "C" void kernel_launch(void* const* d_in, const int* in_sizes, int n_in,
                              void* d_out, int out_size, void* d_ws, size_t ws_size,
                              hipStream_t stream) {
  const float* x    = (const float*)d_in[0];
  const float* Wx_f = (const float*)d_in[1];
  const float* bx_f = (const float*)d_in[2];
  const float* Wh_f = (const float*)d_in[3];
  const float* bh_f = (const float*)d_in[4];
  const float* Wx_b = (const float*)d_in[5];
  const float* bx_b = (const float*)d_in[6];
  const float* Wh_b = (const float*)d_in[7];
  const float* bh_b = (const float*)d_in[8];
  float* out = (float*)d_out;

  if (ws_size < WS_NEED) {
    k_sentinel<<<(out_size + 255) / 256, 256, 0, stream>>>(out, out_size);
    return;
  }

  char* ws = (char*)d_ws;
  unsigned short* xp    = (unsigned short*)(ws + OFF_XP);
  unsigned short* xb    = (unsigned short*)(ws + OFF_XB);
  unsigned short* W2x   = (unsigned short*)(ws + OFF_W2X);
  unsigned short* W2h   = (unsigned short*)(ws + OFF_W2H);
  float*          bias2 = (float*)(ws + OFF_BIAS);
  unsigned short* hbuf  = (unsigned short*)(ws + OFF_HB);
  unsigned*       bar   = (unsigned*)(ws + OFF_BAR);

  k_cvt_weights<<<(2 * NROW * KD) / 256, 256, 0, stream>>>(
      Wx_f, Wh_f, Wx_b, Wh_b, bx_f, bh_f, bx_b, bh_b, W2x, W2h, bias2);
  k_cvt_x<<<(B_ * T_ * I_) / 256, 256, 0, stream>>>(x, xb);
  k_zero_h<<<(2 * 2 * B_ * H_) / 256, 256, 0, stream>>>(hbuf, bar);
  k_gemm_xp<<<2 * 20 * 256, 256, 0, stream>>>(W2x, xb, bias2, xp);
  k_recurrent<<<NBLK_REC, 256, 0, stream>>>(W2h, xp, hbuf, out, bar);
}

// Round 5
// 4335.840 us; speedup vs baseline: 1.5803x; 1.0158x over previous
//
#include <hip/hip_runtime.h>
#include <hip/hip_bf16.h>

// Problem constants
#define B_   64
#define T_   512
#define I_   512
#define H_   512
#define G_   5
#define NROW 2560   // G*H gate rows per direction
#define KD   512    // K depth (I or H)
#define NBLK_REC 128

typedef __attribute__((ext_vector_type(8))) __bf16 bf16x8;
typedef __attribute__((ext_vector_type(4))) float  f32x4;
typedef __attribute__((ext_vector_type(2))) unsigned long long u64x2;
typedef unsigned long long u64;

#define MFMA16(A, Bf, C) __builtin_amdgcn_mfma_f32_16x16x32_bf16(A, Bf, C, 0, 0, 0)

__device__ __forceinline__ unsigned short f2bf(float f) {
  unsigned u = __builtin_bit_cast(unsigned, f);
  u = (u + 0x7fffu + ((u >> 16) & 1u)) >> 16;   // RNE
  return (unsigned short)u;
}
__device__ __forceinline__ float bf2f(unsigned short s) {
  unsigned u = ((unsigned)s) << 16;
  return __builtin_bit_cast(float, u);
}
__device__ __forceinline__ float sigm(float x) { return 1.f / (1.f + __expf(-x)); }
__device__ __forceinline__ float tanh_fast(float x) {
  return 1.f - 2.f / (__expf(2.f * x) + 1.f);
}

// ---------------- ws layout (bytes) ----------------
#define OFF_XP   ((size_t)0)
#define OFF_XB   ((size_t)335544320)
#define OFF_W2X  ((size_t)369098752)
#define OFF_W2H  ((size_t)374341632)
#define OFF_BIAS ((size_t)379584512)
#define OFF_HB   ((size_t)379604992)
#define OFF_BAR  ((size_t)379867136)
#define WS_NEED  ((size_t)379871232)

// ---------------- sentinel (ws too small) ----------------
__global__ void k_sentinel(float* out, int n) {
  int i = blockIdx.x * 256 + threadIdx.x;
  if (i < n) out[i] = 10000.0f;
}

// ---------------- converts ----------------
__global__ void k_cvt_weights(const float* __restrict__ Wx_f, const float* __restrict__ Wh_f,
                              const float* __restrict__ Wx_b, const float* __restrict__ Wh_b,
                              const float* __restrict__ bx_f, const float* __restrict__ bh_f,
                              const float* __restrict__ bx_b, const float* __restrict__ bh_b,
                              unsigned short* __restrict__ W2x, unsigned short* __restrict__ W2h,
                              float* __restrict__ bias2) {
  int idx = blockIdx.x * 256 + threadIdx.x;       // exactly 2*NROW*KD threads
  int dir = idx / (NROW * KD);
  int r   = idx % (NROW * KD);
  W2x[idx] = f2bf(dir ? Wx_b[r] : Wx_f[r]);
  W2h[idx] = f2bf(dir ? Wh_b[r] : Wh_f[r]);
  if (idx < 2 * NROW) {
    int d2 = idx / NROW, n = idx % NROW;
    bias2[idx] = d2 ? (bx_b[n] + bh_b[n]) : (bx_f[n] + bh_f[n]);
  }
}

__global__ void k_cvt_x(const float* __restrict__ x, unsigned short* __restrict__ xb) {
  int idx = blockIdx.x * 256 + threadIdx.x;       // exactly B*T*I threads
  xb[idx] = f2bf(x[idx]);
}

__global__ void k_zero_h(unsigned short* __restrict__ hb, unsigned* __restrict__ bar) {
  int idx = blockIdx.x * 256 + threadIdx.x;       // exactly 2*2*B*H threads
  hb[idx] = 0;
  if (idx < 1024) bar[idx] = 0;
}

// ---------------- phase 1: xp = Wx · x^T (+bias), both dirs ----------------
__global__ __launch_bounds__(256) void k_gemm_xp(
    const unsigned short* __restrict__ W2x,   // [2][NROW][KD]
    const unsigned short* __restrict__ xb,    // [B][T][I]
    const float* __restrict__ bias2,          // [2][NROW]
    unsigned short* __restrict__ xp)          // [2][T][NROW][B]
{
  const int tid = threadIdx.x;
  const int lane = tid & 63, wv = tid >> 6;
  int bz = blockIdx.x;
  const int dir = bz / (20 * 256); bz %= (20 * 256);
  const int nblk = bz / 256, mblk = bz % 256;
  const int n0 = nblk * 128, m0 = mblk * 128;
  const int l15 = lane & 15, l4 = lane >> 4;
  const int nh = wv >> 1, mh = wv & 1;

  __shared__ unsigned short Al[128 * 72];
  __shared__ unsigned short Bl[128 * 72];

  const unsigned short* Wd = W2x + (size_t)dir * NROW * KD;

  f32x4 acc[4][4];
  f32x4 zz = {0.f, 0.f, 0.f, 0.f};
#pragma unroll
  for (int i = 0; i < 4; ++i)
#pragma unroll
    for (int j = 0; j < 4; ++j) acc[i][j] = zz;

  for (int k0 = 0; k0 < KD; k0 += 64) {
#pragma unroll
    for (int j = 0; j < 4; ++j) {
      int sg = j * 256 + tid;
      int row = sg >> 3, ko = (sg & 7) * 8;
      bf16x8 va = *(const bf16x8*)(Wd + (size_t)(n0 + row) * KD + k0 + ko);
      *(bf16x8*)(Al + row * 72 + ko) = va;
      int m = m0 + row;
      int ss = m >> 6, b = m & 63;
      int trow = dir ? (T_ - 1 - ss) : ss;
      bf16x8 vb = *(const bf16x8*)(xb + ((size_t)b * T_ + trow) * I_ + k0 + ko);
      *(bf16x8*)(Bl + row * 72 + ko) = vb;
    }
    __syncthreads();
#pragma unroll
    for (int kk = 0; kk < 2; ++kk) {
      bf16x8 af[4], bfr[4];
#pragma unroll
      for (int f = 0; f < 4; ++f) {
        af[f]  = *(const bf16x8*)(Al + (nh * 64 + f * 16 + l15) * 72 + kk * 32 + l4 * 8);
        bfr[f] = *(const bf16x8*)(Bl + (mh * 64 + f * 16 + l15) * 72 + kk * 32 + l4 * 8);
      }
#pragma unroll
      for (int fi = 0; fi < 4; ++fi)
#pragma unroll
        for (int fj = 0; fj < 4; ++fj)
          acc[fi][fj] = MFMA16(af[fi], bfr[fj], acc[fi][fj]);
    }
    __syncthreads();
  }

#pragma unroll
  for (int fi = 0; fi < 4; ++fi) {
#pragma unroll
    for (int fj = 0; fj < 4; ++fj) {
#pragma unroll
      for (int r = 0; r < 4; ++r) {
        int n = n0 + nh * 64 + fi * 16 + l4 * 4 + r;
        int m = m0 + mh * 64 + fj * 16 + l15;
        int ss = m >> 6, b = m & 63;
        float v = acc[fi][fj][r] + bias2[dir * NROW + n];
        xp[(((size_t)dir * T_ + ss) * NROW + n) * 64 + b] = f2bf(v);
      }
    }
  }
}

// ---------------- phase 2: persistent recurrent kernel ----------------
// 128 blocks (dir = bid&1, ublk = bid>>1 owns 8 units), 256 threads = 4 waves.
// Wh fragments are loop-invariant readonly loads: NO memory clobbers in the
// step loop (the only drain is __builtin_amdgcn_s_waitcnt, IntrNoMem), so the
// compiler can keep all 48 frags (192 VGPRs) live across all 512 steps.
__global__ __launch_bounds__(256, 1) void k_recurrent(
    const unsigned short* __restrict__ W2h,  // [2][NROW][KD]
    const unsigned short* __restrict__ xp,   // [2][T][NROW][B]
    unsigned short* __restrict__ hbuf,       // [2][2][B][H]
    float* __restrict__ out,                 // [B][T][2H]
    unsigned* __restrict__ bar)              // [2][64] per-block epoch flags
{
  const int tid = threadIdx.x;
  const int lane = tid & 63, wv = tid >> 6;
  const int bid = blockIdx.x;
  const int dir = bid & 1;
  const int ublk = bid >> 1;
  const int l15 = lane & 15, l4 = lane >> 4;

  __shared__ float gate_lds[64][52];
  __shared__ unsigned short xp_lds[5][8][72];

  f32x4 zz = {0.f, 0.f, 0.f, 0.f};
  const bf16x8 zfrag = __builtin_bit_cast(bf16x8, zz);

  // recurrent-weight fragments — intended register-resident for all 512 steps
  bf16x8 wfrag[3][16];
#pragma unroll
  for (int nt = 0; nt < 3; ++nt) {
    int r = nt * 16 + l15;
#pragma unroll
    for (int ks = 0; ks < 16; ++ks) {
      if (r < 40) {
        int g = r >> 3, ul = r & 7;
        const unsigned short* wrow =
            W2h + ((size_t)dir * NROW + g * H_ + ublk * 8 + ul) * KD;
        wfrag[nt][ks] = *(const bf16x8*)(wrow + ks * 32 + l4 * 8);
      } else {
        wfrag[nt][ks] = zfrag;
      }
    }
  }

  // cell ownership: thread -> (b = tid>>2, units u0..u0+1 with u0 = ublk*8 + (tid&3)*2)
  const int bb  = tid >> 2;
  const int up  = (tid & 3) * 2;
  const int ubase = ublk * 8 + up;
  float kst0 = 0.f, kpst0 = 0.f, kst1 = 0.f, kpst1 = 0.f;

  const unsigned short* xpd = xp + (size_t)dir * T_ * NROW * 64;
  const unsigned short* hc = hbuf + (size_t)dir * B_ * H_;              // buf 0
  unsigned short*       hn = hbuf + (size_t)(2 + dir) * B_ * H_;        // buf 1
  unsigned* flagsd = bar + dir * 64;

  // stage xp regs for step 0 (coalesced u32 cooperative loads)
  unsigned xr0, xr1, xr2, xr3, xr4;
  {
    const unsigned short* base = xpd + (size_t)ublk * 8 * 64;
    xr0 = ((const unsigned*)(base + 0 * H_ * 64))[tid];
    xr1 = ((const unsigned*)(base + 1 * H_ * 64))[tid];
    xr2 = ((const unsigned*)(base + 2 * H_ * 64))[tid];
    xr3 = ((const unsigned*)(base + 3 * H_ * 64))[tid];
    xr4 = ((const unsigned*)(base + 4 * H_ * 64))[tid];
  }
  const int xu = tid >> 5, xb2 = (tid & 31) * 2;

  for (int s = 0; s < T_; ++s) {
    // commit staged xp for this step into LDS
    *(unsigned*)&xp_lds[0][xu][xb2] = xr0;
    *(unsigned*)&xp_lds[1][xu][xb2] = xr1;
    *(unsigned*)&xp_lds[2][xu][xb2] = xr2;
    *(unsigned*)&xp_lds[3][xu][xb2] = xr3;
    *(unsigned*)&xp_lds[4][xu][xb2] = xr4;

    // h loads: L2-bypassing u64 atomic loads (fresh cross-XCD data)
    const u64* hq = (const u64*)(hc + (size_t)(wv * 16 + l15) * H_ + l4 * 8);
    u64 hlo[16], hhi[16];
#pragma unroll
    for (int ks = 0; ks < 16; ++ks) {
      hlo[ks] = __hip_atomic_load(hq + ks * 8,     __ATOMIC_RELAXED, __HIP_MEMORY_SCOPE_AGENT);
      hhi[ks] = __hip_atomic_load(hq + ks * 8 + 1, __ATOMIC_RELAXED, __HIP_MEMORY_SCOPE_AGENT);
    }
    // 6 accumulator chains (depth 8 each) to cut serial MFMA latency
    f32x4 a0a = zz, a0b = zz, a1a = zz, a1b = zz, a2a = zz, a2b = zz;
#pragma unroll
    for (int ks = 0; ks < 8; ++ks) {
      u64x2 t2 = {hlo[ks], hhi[ks]};
      bf16x8 a = __builtin_bit_cast(bf16x8, t2);
      a0a = MFMA16(a, wfrag[0][ks], a0a);
      a1a = MFMA16(a, wfrag[1][ks], a1a);
      a2a = MFMA16(a, wfrag[2][ks], a2a);
    }
#pragma unroll
    for (int ks = 8; ks < 16; ++ks) {
      u64x2 t2 = {hlo[ks], hhi[ks]};
      bf16x8 a = __builtin_bit_cast(bf16x8, t2);
      a0b = MFMA16(a, wfrag[0][ks], a0b);
      a1b = MFMA16(a, wfrag[1][ks], a1b);
      a2b = MFMA16(a, wfrag[2][ks], a2b);
    }
    f32x4 acc0 = a0a + a0b, acc1 = a1a + a1b, acc2 = a2a + a2b;

    // dump D: row(M)=batch=(l>>4)*4+r, col(N)=gate row=l&15
#pragma unroll
    for (int rr = 0; rr < 4; ++rr) {
      int b = wv * 16 + l4 * 4 + rr;
      gate_lds[b][0 + l15]  = acc0[rr];
      gate_lds[b][16 + l15] = acc1[rr];
      gate_lds[b][32 + l15] = acc2[rr];
    }
    __syncthreads();

    // pointwise for cells (bb, ubase) and (bb, ubase+1)
    float p0 = gate_lds[bb][0 * 8 + up]     + bf2f(xp_lds[0][up][bb]);
    float p1 = gate_lds[bb][1 * 8 + up]     + bf2f(xp_lds[1][up][bb]);
    float p2 = gate_lds[bb][2 * 8 + up]     + bf2f(xp_lds[2][up][bb]);
    float p3 = gate_lds[bb][3 * 8 + up]     + bf2f(xp_lds[3][up][bb]);
    float p4 = gate_lds[bb][4 * 8 + up]     + bf2f(xp_lds[4][up][bb]);
    float q0 = gate_lds[bb][0 * 8 + up + 1] + bf2f(xp_lds[0][up + 1][bb]);
    float q1 = gate_lds[bb][1 * 8 + up + 1] + bf2f(xp_lds[1][up + 1][bb]);
    float q2 = gate_lds[bb][2 * 8 + up + 1] + bf2f(xp_lds[2][up + 1][bb]);
    float q3 = gate_lds[bb][3 * 8 + up + 1] + bf2f(xp_lds[3][up + 1][bb]);
    float q4 = gate_lds[bb][4 * 8 + up + 1] + bf2f(xp_lds[4][up + 1][bb]);

    float f0 = sigm(p0), i0 = sigm(p1), o0 = sigm(p2), uu0 = sigm(p3), tk0 = tanh_fast(p4);
    kpst0 = uu0 * tk0 + (1.f - uu0) * kpst0;
    kst0  = f0 * kst0 + i0 * kpst0;
    float hv0 = o0 * tanh_fast(kst0);

    float f1 = sigm(q0), i1 = sigm(q1), o1 = sigm(q2), uu1 = sigm(q3), tk1 = tanh_fast(q4);
    kpst1 = uu1 * tk1 + (1.f - uu1) * kpst1;
    kst1  = f1 * kst1 + i1 * kpst1;
    float hv1 = o1 * tanh_fast(kst1);

    // publish h (agent-scope, write-through to L3) — the critical-path store
    unsigned hw = (unsigned)f2bf(hv0) | ((unsigned)f2bf(hv1) << 16);
    __hip_atomic_store((unsigned*)(hn + (size_t)bb * H_ + ubase), hw,
                       __ATOMIC_RELAXED, __HIP_MEMORY_SCOPE_AGENT);

    int tout = dir ? (T_ - 1 - s) : s;
    if (s + 1 < T_) {
      // drain the h store before signaling. IntrNoMem side-effecting wait:
      // ordered vs memory ops, but does NOT invalidate cached readonly values
      // (keeps wfrag register-resident).
      __builtin_amdgcn_s_waitcnt(0);
      // off-critical-path: out store + next xp prefetch (overlap the poll)
      float2 ov = {hv0, hv1};
      *(float2*)&out[((size_t)bb * T_ + tout) * (2 * H_) + dir * H_ + ubase] = ov;
      const unsigned short* nbase = xpd + (size_t)(s + 1) * NROW * 64 + (size_t)ublk * 8 * 64;
      xr0 = ((const unsigned*)(nbase + 0 * H_ * 64))[tid];
      xr1 = ((const unsigned*)(nbase + 1 * H_ * 64))[tid];
      xr2 = ((const unsigned*)(nbase + 2 * H_ * 64))[tid];
      xr3 = ((const unsigned*)(nbase + 3 * H_ * 64))[tid];
      xr4 = ((const unsigned*)(nbase + 4 * H_ * 64))[tid];

      __syncthreads();                       // all waves' h stores are drained
      if (wv == 0) {
        if (lane == 0)
          __hip_atomic_store(&flagsd[ublk], (unsigned)(s + 1),
                             __ATOMIC_RELAXED, __HIP_MEMORY_SCOPE_AGENT);
        unsigned tgt = (unsigned)(s + 1);
        for (;;) {
          unsigned v = __hip_atomic_load(&flagsd[lane],
                                         __ATOMIC_RELAXED, __HIP_MEMORY_SCOPE_AGENT);
          if (!__any(v < tgt)) break;
          __builtin_amdgcn_s_sleep(1);       // throttle poll
        }
      }
      __syncthreads();                       // release all waves
    } else {
      float2 ov = {hv0, hv1};
      *(float2*)&out[((size_t)bb * T_ + tout) * (2 * H_) + dir * H_ + ubase] = ov;
    }

    const unsigned short* tmp = hc; hc = hn; hn = (unsigned short*)tmp;
  }
}

// ---------------- launch ----------------
extern "C" void kernel_launch(void* const* d_in, const int* in_sizes, int n_in,
                              void* d_out, int out_size, void* d_ws, size_t ws_size,
                              hipStream_t stream) {
  const float* x    = (const float*)d_in[0];
  const float* Wx_f = (const float*)d_in[1];
  const float* bx_f = (const float*)d_in[2];
  const float* Wh_f = (const float*)d_in[3];
  const float* bh_f = (const float*)d_in[4];
  const float* Wx_b = (const float*)d_in[5];
  const float* bx_b = (const float*)d_in[6];
  const float* Wh_b = (const float*)d_in[7];
  const float* bh_b = (const float*)d_in[8];
  float* out = (float*)d_out;

  if (ws_size < WS_NEED) {
    k_sentinel<<<(out_size + 255) / 256, 256, 0, stream>>>(out, out_size);
    return;
  }

  char* ws = (char*)d_ws;
  unsigned short* xp    = (unsigned short*)(ws + OFF_XP);
  unsigned short* xb    = (unsigned short*)(ws + OFF_XB);
  unsigned short* W2x   = (unsigned short*)(ws + OFF_W2X);
  unsigned short* W2h   = (unsigned short*)(ws + OFF_W2H);
  float*          bias2 = (float*)(ws + OFF_BIAS);
  unsigned short* hbuf  = (unsigned short*)(ws + OFF_HB);
  unsigned*       bar   = (unsigned*)(ws + OFF_BAR);

  k_cvt_weights<<<(2 * NROW * KD) / 256, 256, 0, stream>>>(
      Wx_f, Wh_f, Wx_b, Wh_b, bx_f, bh_f, bx_b, bh_b, W2x, W2h, bias2);
  k_cvt_x<<<(B_ * T_ * I_) / 256, 256, 0, stream>>>(x, xb);
  k_zero_h<<<(2 * 2 * B_ * H_) / 256, 256, 0, stream>>>(hbuf, bar);
  k_gemm_xp<<<2 * 20 * 256, 256, 0, stream>>>(W2x, xb, bias2, xp);
  k_recurrent<<<NBLK_REC, 256, 0, stream>>>(W2h, xp, hbuf, out, bar);
}

// Round 6
// 2745.794 us; speedup vs baseline: 2.4954x; 1.5791x over previous
//
#include <hip/hip_runtime.h>
#include <hip/hip_bf16.h>

// Problem constants
#define B_   64
#define T_   512
#define I_   512
#define H_   512
#define G_   5
#define NROW 2560   // G*H gate rows per direction
#define KD   512    // K depth (I or H)
#define NBLK_REC 128
#define WSTRIDE 520 // padded LDS row stride (ushorts) for bank spread

typedef __attribute__((ext_vector_type(8))) __bf16 bf16x8;
typedef __attribute__((ext_vector_type(4))) float  f32x4;
typedef __attribute__((ext_vector_type(2))) unsigned long long u64x2;
typedef unsigned long long u64;

#define MFMA16(A, Bf, C) __builtin_amdgcn_mfma_f32_16x16x32_bf16(A, Bf, C, 0, 0, 0)

__device__ __forceinline__ unsigned short f2bf(float f) {
  unsigned u = __builtin_bit_cast(unsigned, f);
  u = (u + 0x7fffu + ((u >> 16) & 1u)) >> 16;   // RNE
  return (unsigned short)u;
}
__device__ __forceinline__ float bf2f(unsigned short s) {
  unsigned u = ((unsigned)s) << 16;
  return __builtin_bit_cast(float, u);
}
__device__ __forceinline__ float sigm(float x) { return 1.f / (1.f + __expf(-x)); }
__device__ __forceinline__ float tanh_fast(float x) {
  return 1.f - 2.f / (__expf(2.f * x) + 1.f);
}

// ---------------- ws layout (bytes) ----------------
#define OFF_XP   ((size_t)0)
#define OFF_XB   ((size_t)335544320)
#define OFF_W2X  ((size_t)369098752)
#define OFF_W2H  ((size_t)374341632)
#define OFF_BIAS ((size_t)379584512)
#define OFF_HB   ((size_t)379604992)
#define OFF_BAR  ((size_t)379867136)
#define WS_NEED  ((size_t)379871232)

// ---------------- sentinel (ws too small) ----------------
__global__ void k_sentinel(float* out, int n) {
  int i = blockIdx.x * 256 + threadIdx.x;
  if (i < n) out[i] = 10000.0f;
}

// ---------------- converts ----------------
__global__ void k_cvt_weights(const float* __restrict__ Wx_f, const float* __restrict__ Wh_f,
                              const float* __restrict__ Wx_b, const float* __restrict__ Wh_b,
                              const float* __restrict__ bx_f, const float* __restrict__ bh_f,
                              const float* __restrict__ bx_b, const float* __restrict__ bh_b,
                              unsigned short* __restrict__ W2x, unsigned short* __restrict__ W2h,
                              float* __restrict__ bias2) {
  int idx = blockIdx.x * 256 + threadIdx.x;       // exactly 2*NROW*KD threads
  int dir = idx / (NROW * KD);
  int r   = idx % (NROW * KD);
  W2x[idx] = f2bf(dir ? Wx_b[r] : Wx_f[r]);
  W2h[idx] = f2bf(dir ? Wh_b[r] : Wh_f[r]);
  if (idx < 2 * NROW) {
    int d2 = idx / NROW, n = idx % NROW;
    bias2[idx] = d2 ? (bx_b[n] + bh_b[n]) : (bx_f[n] + bh_f[n]);
  }
}

__global__ void k_cvt_x(const float* __restrict__ x, unsigned short* __restrict__ xb) {
  int idx = blockIdx.x * 256 + threadIdx.x;       // exactly B*T*I threads
  xb[idx] = f2bf(x[idx]);
}

__global__ void k_zero_h(unsigned short* __restrict__ hb, unsigned* __restrict__ bar) {
  int idx = blockIdx.x * 256 + threadIdx.x;       // exactly 2*2*B*H threads
  hb[idx] = 0;
  if (idx < 1024) bar[idx] = 0;
}

// ---------------- phase 1: xp = Wx · x^T (+bias), both dirs ----------------
__global__ __launch_bounds__(256) void k_gemm_xp(
    const unsigned short* __restrict__ W2x,   // [2][NROW][KD]
    const unsigned short* __restrict__ xb,    // [B][T][I]
    const float* __restrict__ bias2,          // [2][NROW]
    unsigned short* __restrict__ xp)          // [2][T][NROW][B]
{
  const int tid = threadIdx.x;
  const int lane = tid & 63, wv = tid >> 6;
  int bz = blockIdx.x;
  const int dir = bz / (20 * 256); bz %= (20 * 256);
  const int nblk = bz / 256, mblk = bz % 256;
  const int n0 = nblk * 128, m0 = mblk * 128;
  const int l15 = lane & 15, l4 = lane >> 4;
  const int nh = wv >> 1, mh = wv & 1;

  __shared__ unsigned short Al[128 * 72];
  __shared__ unsigned short Bl[128 * 72];

  const unsigned short* Wd = W2x + (size_t)dir * NROW * KD;

  f32x4 acc[4][4];
  f32x4 zz = {0.f, 0.f, 0.f, 0.f};
#pragma unroll
  for (int i = 0; i < 4; ++i)
#pragma unroll
    for (int j = 0; j < 4; ++j) acc[i][j] = zz;

  for (int k0 = 0; k0 < KD; k0 += 64) {
#pragma unroll
    for (int j = 0; j < 4; ++j) {
      int sg = j * 256 + tid;
      int row = sg >> 3, ko = (sg & 7) * 8;
      bf16x8 va = *(const bf16x8*)(Wd + (size_t)(n0 + row) * KD + k0 + ko);
      *(bf16x8*)(Al + row * 72 + ko) = va;
      int m = m0 + row;
      int ss = m >> 6, b = m & 63;
      int trow = dir ? (T_ - 1 - ss) : ss;
      bf16x8 vb = *(const bf16x8*)(xb + ((size_t)b * T_ + trow) * I_ + k0 + ko);
      *(bf16x8*)(Bl + row * 72 + ko) = vb;
    }
    __syncthreads();
#pragma unroll
    for (int kk = 0; kk < 2; ++kk) {
      bf16x8 af[4], bfr[4];
#pragma unroll
      for (int f = 0; f < 4; ++f) {
        af[f]  = *(const bf16x8*)(Al + (nh * 64 + f * 16 + l15) * 72 + kk * 32 + l4 * 8);
        bfr[f] = *(const bf16x8*)(Bl + (mh * 64 + f * 16 + l15) * 72 + kk * 32 + l4 * 8);
      }
#pragma unroll
      for (int fi = 0; fi < 4; ++fi)
#pragma unroll
        for (int fj = 0; fj < 4; ++fj)
          acc[fi][fj] = MFMA16(af[fi], bfr[fj], acc[fi][fj]);
    }
    __syncthreads();
  }

#pragma unroll
  for (int fi = 0; fi < 4; ++fi) {
#pragma unroll
    for (int fj = 0; fj < 4; ++fj) {
#pragma unroll
      for (int r = 0; r < 4; ++r) {
        int n = n0 + nh * 64 + fi * 16 + l4 * 4 + r;
        int m = m0 + mh * 64 + fj * 16 + l15;
        int ss = m >> 6, b = m & 63;
        float v = acc[fi][fj][r] + bias2[dir * NROW + n];
        xp[(((size_t)dir * T_ + ss) * NROW + n) * 64 + b] = f2bf(v);
      }
    }
  }
}

// ---------------- phase 2: persistent recurrent kernel ----------------
// 128 blocks (dir = bid&1, ublk = bid>>1 owns 8 units), 256 threads = 4 waves.
// Wh lives in LDS (40 x 520 ushorts). Per step each wave re-reads its 48
// B-fragments via ds_read_b128 ISSUED BEFORE the flag poll (static data, no
// dep) and pinned there with lgkmcnt(0)+sched_barrier, so LDS latency hides
// under the poll. All waves poll independently (no release barrier).
// h layout is block-major [dir][buf][ublk][b][8u] -> coalesced 1KB store.
__global__ __launch_bounds__(256, 1) void k_recurrent(
    const unsigned short* __restrict__ W2h,  // [2][NROW][KD]
    const unsigned short* __restrict__ xp,   // [2][T][NROW][B]
    unsigned short* __restrict__ hbuf,       // [2][2][64][64][8] blk-major
    float* __restrict__ out,                 // [B][T][2H]
    unsigned* __restrict__ bar)              // [2][64] per-block epoch flags
{
  const int tid = threadIdx.x;
  const int lane = tid & 63, wv = tid >> 6;
  const int bid = blockIdx.x;
  const int dir = bid & 1;
  const int ublk = bid >> 1;
  const int l15 = lane & 15, l4 = lane >> 4;

  __shared__ float gate_lds[64][52];
  __shared__ unsigned short xp_lds[5][8][72];
  __shared__ unsigned short w_lds[40 * WSTRIDE];

  // ---- stage Wh for this block into LDS (once) ----
#pragma unroll
  for (int it = 0; it < 10; ++it) {
    int seg = it * 256 + tid;            // 2560 segs of 16B
    int r = seg >> 6, c8 = seg & 63;     // local row r (0..39), 16B col index
    int g = r >> 3, ul = r & 7;
    const unsigned short* src =
        W2h + ((size_t)dir * NROW + g * H_ + ublk * 8 + ul) * KD + c8 * 8;
    *(bf16x8*)(w_lds + r * WSTRIDE + c8 * 8) = *(const bf16x8*)src;
  }
  __syncthreads();

  // per-lane fragment base byte offsets (3 n-tiles; pad rows >=40 read row 0)
  int wboff[3];
#pragma unroll
  for (int nt = 0; nt < 3; ++nt) {
    int r = nt * 16 + l15;
    if (r >= 40) r = 0;                  // garbage cols 40-47 never consumed
    wboff[nt] = (r * WSTRIDE + l4 * 8) * 2;
  }
  const char* wp = (const char*)w_lds;

  f32x4 zz = {0.f, 0.f, 0.f, 0.f};

  // weight fragments for step 0
  bf16x8 wf[3][16];
#pragma unroll
  for (int nt = 0; nt < 3; ++nt)
#pragma unroll
    for (int ks = 0; ks < 16; ++ks)
      wf[nt][ks] = *(const bf16x8*)(wp + wboff[nt] + ks * 64);

  // cell ownership: thread -> (b = tid>>2, units ubase..ubase+1)
  const int bb  = tid >> 2;
  const int up  = (tid & 3) * 2;
  const int ubase = ublk * 8 + up;
  float kst0 = 0.f, kpst0 = 0.f, kst1 = 0.f, kpst1 = 0.f;

  const unsigned short* xpd = xp + (size_t)dir * T_ * NROW * 64;
  const unsigned short* hc = hbuf + (size_t)dir * B_ * H_;        // buf 0
  unsigned short*       hn = hbuf + (size_t)(2 + dir) * B_ * H_;  // buf 1
  unsigned* flagsd = bar + dir * 64;

  // xp regs for step 0
  unsigned xr0, xr1, xr2, xr3, xr4;
  {
    const unsigned short* base = xpd + (size_t)ublk * 8 * 64;
    xr0 = ((const unsigned*)(base + 0 * H_ * 64))[tid];
    xr1 = ((const unsigned*)(base + 1 * H_ * 64))[tid];
    xr2 = ((const unsigned*)(base + 2 * H_ * 64))[tid];
    xr3 = ((const unsigned*)(base + 3 * H_ * 64))[tid];
    xr4 = ((const unsigned*)(base + 4 * H_ * 64))[tid];
  }
  const int xu = tid >> 5, xb2 = (tid & 31) * 2;
  const int hbase = (wv * 16 + l15) * 2;       // u64 units within a 1KB chunk set

  for (int s = 0; s < T_; ++s) {
    // h loads first (agent-scope u64 atomics from L3, block-major layout)
    const u64* hq = (const u64*)hc;
    u64 hlo[16], hhi[16];
#pragma unroll
    for (int ks = 0; ks < 16; ++ks) {
      int ci = (ks * 4 + l4) * 128 + hbase;
      hlo[ks] = __hip_atomic_load(hq + ci,     __ATOMIC_RELAXED, __HIP_MEMORY_SCOPE_AGENT);
      hhi[ks] = __hip_atomic_load(hq + ci + 1, __ATOMIC_RELAXED, __HIP_MEMORY_SCOPE_AGENT);
    }

    // commit staged xp for this step into LDS
    *(unsigned*)&xp_lds[0][xu][xb2] = xr0;
    *(unsigned*)&xp_lds[1][xu][xb2] = xr1;
    *(unsigned*)&xp_lds[2][xu][xb2] = xr2;
    *(unsigned*)&xp_lds[3][xu][xb2] = xr3;
    *(unsigned*)&xp_lds[4][xu][xb2] = xr4;

    // 6 accumulator chains (depth 8) over K=512
    f32x4 a0a = zz, a0b = zz, a1a = zz, a1b = zz, a2a = zz, a2b = zz;
#pragma unroll
    for (int ks = 0; ks < 8; ++ks) {
      u64x2 t2 = {hlo[ks], hhi[ks]};
      bf16x8 a = __builtin_bit_cast(bf16x8, t2);
      a0a = MFMA16(a, wf[0][ks], a0a);
      a1a = MFMA16(a, wf[1][ks], a1a);
      a2a = MFMA16(a, wf[2][ks], a2a);
    }
#pragma unroll
    for (int ks = 8; ks < 16; ++ks) {
      u64x2 t2 = {hlo[ks], hhi[ks]};
      bf16x8 a = __builtin_bit_cast(bf16x8, t2);
      a0b = MFMA16(a, wf[0][ks], a0b);
      a1b = MFMA16(a, wf[1][ks], a1b);
      a2b = MFMA16(a, wf[2][ks], a2b);
    }
    f32x4 acc0 = a0a + a0b, acc1 = a1a + a1b, acc2 = a2a + a2b;

    // dump D: row(M)=batch=(l>>4)*4+rr, col(N)=gate row=l&15
#pragma unroll
    for (int rr = 0; rr < 4; ++rr) {
      int b = wv * 16 + l4 * 4 + rr;
      gate_lds[b][0 + l15]  = acc0[rr];
      gate_lds[b][16 + l15] = acc1[rr];
      gate_lds[b][32 + l15] = acc2[rr];
    }
    __syncthreads();                         // sync#1: gates ready

    // pointwise for cells (bb, ubase) and (bb, ubase+1)
    float p0 = gate_lds[bb][0 * 8 + up]     + bf2f(xp_lds[0][up][bb]);
    float p1 = gate_lds[bb][1 * 8 + up]     + bf2f(xp_lds[1][up][bb]);
    float p2 = gate_lds[bb][2 * 8 + up]     + bf2f(xp_lds[2][up][bb]);
    float p3 = gate_lds[bb][3 * 8 + up]     + bf2f(xp_lds[3][up][bb]);
    float p4 = gate_lds[bb][4 * 8 + up]     + bf2f(xp_lds[4][up][bb]);
    float q0 = gate_lds[bb][0 * 8 + up + 1] + bf2f(xp_lds[0][up + 1][bb]);
    float q1 = gate_lds[bb][1 * 8 + up + 1] + bf2f(xp_lds[1][up + 1][bb]);
    float q2 = gate_lds[bb][2 * 8 + up + 1] + bf2f(xp_lds[2][up + 1][bb]);
    float q3 = gate_lds[bb][3 * 8 + up + 1] + bf2f(xp_lds[3][up + 1][bb]);
    float q4 = gate_lds[bb][4 * 8 + up + 1] + bf2f(xp_lds[4][up + 1][bb]);

    float f0 = sigm(p0), i0 = sigm(p1), o0 = sigm(p2), uu0 = sigm(p3), tk0 = tanh_fast(p4);
    kpst0 = uu0 * tk0 + (1.f - uu0) * kpst0;
    kst0  = f0 * kst0 + i0 * kpst0;
    float hv0 = o0 * tanh_fast(kst0);

    float f1 = sigm(q0), i1 = sigm(q1), o1 = sigm(q2), uu1 = sigm(q3), tk1 = tanh_fast(q4);
    kpst1 = uu1 * tk1 + (1.f - uu1) * kpst1;
    kst1  = f1 * kst1 + i1 * kpst1;
    float hv1 = o1 * tanh_fast(kst1);

    // publish h: coalesced block-major store (1KB per block, L2-bypass)
    unsigned hw = (unsigned)f2bf(hv0) | ((unsigned)f2bf(hv1) << 16);
    __hip_atomic_store((unsigned*)((char*)hn + ublk * 1024 + bb * 16 + up * 2), hw,
                       __ATOMIC_RELAXED, __HIP_MEMORY_SCOPE_AGENT);
    int tout = dir ? (T_ - 1 - s) : s;
    float2 ov = {hv0, hv1};
    *(float2*)&out[((size_t)bb * T_ + tout) * (2 * H_) + dir * H_ + ubase] = ov;

    if (s + 1 < T_) {
      __syncthreads();                       // sync#2: arrival (drains stores)
      if (tid == 0)
        __hip_atomic_store(&flagsd[ublk], (unsigned)(s + 1),
                           __ATOMIC_RELAXED, __HIP_MEMORY_SCOPE_AGENT);

      // work during the wait: xp prefetch (s+1) + weight frag re-reads
      const unsigned short* nbase =
          xpd + (size_t)(s + 1) * NROW * 64 + (size_t)ublk * 8 * 64;
      xr0 = ((const unsigned*)(nbase + 0 * H_ * 64))[tid];
      xr1 = ((const unsigned*)(nbase + 1 * H_ * 64))[tid];
      xr2 = ((const unsigned*)(nbase + 2 * H_ * 64))[tid];
      xr3 = ((const unsigned*)(nbase + 3 * H_ * 64))[tid];
      xr4 = ((const unsigned*)(nbase + 4 * H_ * 64))[tid];
#pragma unroll
      for (int nt = 0; nt < 3; ++nt)
#pragma unroll
        for (int ks = 0; ks < 16; ++ks)
          wf[nt][ks] = *(const bf16x8*)(wp + wboff[nt] + ks * 64);
      asm volatile("s_waitcnt lgkmcnt(0)");  // materialize wf before the poll
      __builtin_amdgcn_sched_barrier(0);     // pin: nothing moves across

      // every wave polls the 64 per-block flags of its direction
      unsigned tgt = (unsigned)(s + 1);
      for (;;) {
        unsigned v = __hip_atomic_load(&flagsd[lane],
                                       __ATOMIC_RELAXED, __HIP_MEMORY_SCOPE_AGENT);
        if (!__any(v < tgt)) break;
        __builtin_amdgcn_s_sleep(1);
      }
      __builtin_amdgcn_sched_barrier(0);     // pin: h loads stay below the poll
    }

    const unsigned short* tmp = hc; hc = hn; hn = (unsigned short*)tmp;
  }
}

// ---------------- launch ----------------
extern "C" void kernel_launch(void* const* d_in, const int* in_sizes, int n_in,
                              void* d_out, int out_size, void* d_ws, size_t ws_size,
                              hipStream_t stream) {
  const float* x    = (const float*)d_in[0];
  const float* Wx_f = (const float*)d_in[1];
  const float* bx_f = (const float*)d_in[2];
  const float* Wh_f = (const float*)d_in[3];
  const float* bh_f = (const float*)d_in[4];
  const float* Wx_b = (const float*)d_in[5];
  const float* bx_b = (const float*)d_in[6];
  const float* Wh_b = (const float*)d_in[7];
  const float* bh_b = (const float*)d_in[8];
  float* out = (float*)d_out;

  if (ws_size < WS_NEED) {
    k_sentinel<<<(out_size + 255) / 256, 256, 0, stream>>>(out, out_size);
    return;
  }

  char* ws = (char*)d_ws;
  unsigned short* xp    = (unsigned short*)(ws + OFF_XP);
  unsigned short* xb    = (unsigned short*)(ws + OFF_XB);
  unsigned short* W2x   = (unsigned short*)(ws + OFF_W2X);
  unsigned short* W2h   = (unsigned short*)(ws + OFF_W2H);
  float*          bias2 = (float*)(ws + OFF_BIAS);
  unsigned short* hbuf  = (unsigned short*)(ws + OFF_HB);
  unsigned*       bar   = (unsigned*)(ws + OFF_BAR);

  k_cvt_weights<<<(2 * NROW * KD) / 256, 256, 0, stream>>>(
      Wx_f, Wh_f, Wx_b, Wh_b, bx_f, bh_f, bx_b, bh_b, W2x, W2h, bias2);
  k_cvt_x<<<(B_ * T_ * I_) / 256, 256, 0, stream>>>(x, xb);
  k_zero_h<<<(2 * 2 * B_ * H_) / 256, 256, 0, stream>>>(hbuf, bar);
  k_gemm_xp<<<2 * 20 * 256, 256, 0, stream>>>(W2x, xb, bias2, xp);
  k_recurrent<<<NBLK_REC, 256, 0, stream>>>(W2h, xp, hbuf, out, bar);
}